// Round 8
// baseline (452.248 us; speedup 1.0000x reference)
//
#include <hip/hip_runtime.h>
#include <hip/hip_bf16.h>
#include <math.h>

// ---------- types ----------
typedef __attribute__((ext_vector_type(8))) short s8v;   // 8 bf16 - MFMA A/B frag
typedef __attribute__((ext_vector_type(4))) short s4v;   // 4 bf16
typedef __attribute__((ext_vector_type(2))) short s2v;   // 2 bf16
typedef __attribute__((ext_vector_type(4))) float f4v;   // 4 f32 - MFMA C/D frag

#define HW   512
#define NIMG 24
#define MAT  (HW*HW)   // 262144
#define NBLK 512       // persistent grid: 2 blocks/CU, guaranteed co-resident

__device__ __forceinline__ unsigned short f2bf(float f) {
  unsigned u = __builtin_bit_cast(unsigned, f);
  u += 0x7fffu + ((u >> 16) & 1u);
  return (unsigned short)(u >> 16);
}
__device__ __forceinline__ float bf2f(unsigned short b) {
  return __builtin_bit_cast(float, (unsigned)b << 16);
}

// fast log1p for z >= 0: v_log_f32 (log2) * ln2, ~1 ulp on 1+z
__device__ __forceinline__ float fast_log1p(float z) {
  float a = 1.0f + z;
  float l;
#if __has_builtin(__builtin_amdgcn_logf)
  l = __builtin_amdgcn_logf(a);
#else
  asm("v_log_f32 %0, %1" : "=v"(l) : "v"(a));
#endif
  return l * 0.69314718055994531f;
}

// ---------- device-wide barrier (monotonic counter; cnt zeroed per launch) ----------
__device__ __forceinline__ void gbar(int* cnt, int target) {
  __syncthreads();
  __threadfence();   // release: prior writes visible device-wide (cross-XCD wb)
  if (threadIdx.x == 0) {
    __hip_atomic_fetch_add(cnt, 1, __ATOMIC_ACQ_REL, __HIP_MEMORY_SCOPE_AGENT);
    while (__hip_atomic_load(cnt, __ATOMIC_ACQUIRE, __HIP_MEMORY_SCOPE_AGENT) < target)
      __builtin_amdgcn_s_sleep(2);
  }
  __syncthreads();
  __threadfence();   // acquire: invalidate caches before reading others' data
}

// ---------- swizzled LDS staging (proven: 0 bank conflicts) ----------
template<int NROWS, int STRB>
__device__ __forceinline__ void stage_tile(const unsigned short* __restrict__ src,
                                           short* lds, int w, int l) {
  #pragma unroll
  for (int c = 0; c < NROWS / 32; ++c) {
    int cid = c * 4 + w;                   // 1KB chunk-groups
    int chunk = cid * 64 + l;              // 16B chunk id within tile
    int row = chunk >> 3, ch = chunk & 7;
    const char* g = (const char*)src + row * STRB + ((ch ^ (row & 7)) << 4);
    __builtin_amdgcn_global_load_lds(
        (const __attribute__((address_space(1))) void*)g,
        (__attribute__((address_space(3))) void*)(lds + (cid << 9)),
        16, 0, 0);
  }
}

__device__ __forceinline__ s8v lds_frag(const short* base, int row, int chunk) {
  return *(const s8v*)((const char*)base + row * 128 + ((chunk ^ (row & 7)) << 4));
}

// ---------- core banded bf16 GEMM (R5-proven 2-phase loop) ----------
template<int IMGW>
__device__ __forceinline__ void gemm_core(
    const unsigned short* __restrict__ Am,   // A + m0*IMGW
    const unsigned short* __restrict__ Bn,   // Bimg + n0*IMGW
    int m0, int band,
    short (*As)[128 * 64], short (*Bs)[64 * 64],
    int w, int lane, int wr, int wc, int lrow, int lq,
    f4v (&acc)[4][2]) {
  constexpr int STRB = IMGW * 2;
  int klo = m0 - band; if (klo < 0) klo = 0; klo >>= 6;
  int hi = m0 + 128 + band; if (hi > IMGW) hi = IMGW;
  int khi = (hi + 63) >> 6;

  stage_tile<128, STRB>(Am + (klo << 6), As[0], w, lane);
  stage_tile<64, STRB>(Bn + (klo << 6), Bs[0], w, lane);
  __syncthreads();
  int cur = 0;

  for (int kb = klo; kb < khi; ++kb) {
    if (kb + 1 < khi) {   // issue next-tile loads BEFORE compute
      stage_tile<128, STRB>(Am + ((kb + 1) << 6), As[cur ^ 1], w, lane);
      stage_tile<64, STRB>(Bn + ((kb + 1) << 6), Bs[cur ^ 1], w, lane);
    }
    #pragma unroll
    for (int kk = 0; kk < 2; ++kk) {
      s8v af[4], bf[2];
      int chunk = (kk << 2) + lq;
      #pragma unroll
      for (int mi = 0; mi < 4; ++mi)
        af[mi] = lds_frag(As[cur], wr + mi * 16 + lrow, chunk);
      #pragma unroll
      for (int ni = 0; ni < 2; ++ni)
        bf[ni] = lds_frag(Bs[cur], wc + ni * 16 + lrow, chunk);
      #pragma unroll
      for (int mi = 0; mi < 4; ++mi)
        #pragma unroll
        for (int ni = 0; ni < 2; ++ni)
          acc[mi][ni] = __builtin_amdgcn_mfma_f32_16x16x32_bf16(af[mi], bf[ni], acc[mi][ni], 0, 0, 0);
    }
    __syncthreads();      // one vmcnt(0)+barrier per tile
    cur ^= 1;
  }
}

// ---------- generic GEMM job: O[img][m][n] = sum_k A[m][k]*B[img][n][k] ----------
template<int IMGW, typename OT>
__device__ __forceinline__ void gemm_body(
    const unsigned short* __restrict__ A,
    const unsigned short* __restrict__ Bm,
    OT* __restrict__ O,
    int band, int bid,
    short (*As)[128 * 64], short (*Bs)[64 * 64], int t) {
  constexpr int NT = IMGW / 64;
  constexpr int TPI = (IMGW / 128) * NT;
  int img = bid / TPI, tl = bid % TPI;
  int m0 = (tl / NT) * 128, n0 = (tl % NT) * 64;

  int lane = t & 63, w = t >> 6;
  int wr = (w >> 1) * 64, wc = (w & 1) * 32;
  int lrow = lane & 15, lq = lane >> 4;

  f4v acc[4][2];
  #pragma unroll
  for (int mi = 0; mi < 4; ++mi)
    #pragma unroll
    for (int ni = 0; ni < 2; ++ni)
      #pragma unroll
      for (int r = 0; r < 4; ++r) acc[mi][ni][r] = 0.f;

  gemm_core<IMGW>(A + m0 * IMGW, Bm + img * IMGW * IMGW + n0 * IMGW,
                  m0, band, As, Bs, w, lane, wr, wc, lrow, lq, acc);

  OT* Ob = O + img * IMGW * IMGW;
  #pragma unroll
  for (int mi = 0; mi < 4; ++mi)
    #pragma unroll
    for (int r = 0; r < 4; ++r) {
      int m = m0 + wr + mi * 16 + lq * 4 + r;
      #pragma unroll
      for (int ni = 0; ni < 2; ++ni) {
        int n = n0 + wc + ni * 16 + lrow;
        float v = acc[mi][ni][r];
        if constexpr (sizeof(OT) == 2) Ob[m * IMGW + n] = f2bf(v);
        else                           Ob[m * IMGW + n] = v;
      }
    }
}

// ---------- bilinear sample of coarse float field ----------
__device__ __forceinline__ float bilerp(const float* __restrict__ Z, int W,
                                        float qm, float qn) {
  float fm = floorf(qm), fn = floorf(qn);
  float am = qm - fm, an = qn - fn;
  int i0 = (int)fm, j0 = (int)fn;
  int i1 = i0 + 1, j1 = j0 + 1;
  i0 = i0 < 0 ? 0 : (i0 > W - 1 ? W - 1 : i0);
  i1 = i1 < 0 ? 0 : (i1 > W - 1 ? W - 1 : i1);
  j0 = j0 < 0 ? 0 : (j0 > W - 1 ? W - 1 : j0);
  j1 = j1 < 0 ? 0 : (j1 > W - 1 ? W - 1 : j1);
  const float* r0 = Z + i0 * W;
  const float* r1 = Z + i1 * W;
  float z0 = r0[j0] + an * (r0[j1] - r0[j0]);
  float z1 = r1[j0] + an * (r1[j1] - r1[j0]);
  return z0 + am * (z1 - z0);
}

// ---------- fine pass2 + combine epilogue (device body) ----------
__device__ __forceinline__ void finep2_body(
    const unsigned short* __restrict__ G,
    const unsigned short* __restrict__ Ut,
    const unsigned short* __restrict__ Xb,
    const float* __restrict__ Z2,
    const float* __restrict__ Z4,
    float* __restrict__ out, int bid,
    short (*As)[128 * 64], short (*Bs)[64 * 64], int t) {
  int img = bid >> 5, tile = bid & 31;
  int m0 = (tile >> 3) * 128, n0 = (tile & 7) * 64;

  int lane = t & 63, w = t >> 6;
  int wr = (w >> 1) * 64, wc = (w & 1) * 32;
  int lrow = lane & 15, lq = lane >> 4;

  f4v acc[4][2];
  #pragma unroll
  for (int mi = 0; mi < 4; ++mi)
    #pragma unroll
    for (int ni = 0; ni < 2; ++ni)
      #pragma unroll
      for (int r = 0; r < 4; ++r) acc[mi][ni][r] = 0.f;

  gemm_core<512>(G + m0 * HW, Ut + img * MAT + n0 * HW,
                 m0, 30, As, Bs, w, lane, wr, wc, lrow, lq, acc);

  const unsigned short* xb = Xb + img * MAT;
  float* O = out + img * MAT;
  const float* z2 = Z2 + img * 65536;
  const float* z4 = Z4 + img * 16384;
  float qn2[2], qn4[2];
  int nn[2];
  #pragma unroll
  for (int ni = 0; ni < 2; ++ni) {
    nn[ni] = n0 + wc + ni * 16 + lrow;
    qn2[ni] = 0.5f * nn[ni] - 0.25f;
    qn4[ni] = 0.25f * nn[ni] - 0.375f;
  }
  #pragma unroll
  for (int mi = 0; mi < 4; ++mi)
    #pragma unroll
    for (int r = 0; r < 4; ++r) {
      int m = m0 + wr + mi * 16 + lq * 4 + r;
      float qm2 = 0.5f * m - 0.25f;
      float qm4 = 0.25f * m - 0.375f;
      #pragma unroll
      for (int ni = 0; ni < 2; ++ni) {
        int idx = m * HW + nn[ni];
        float z80v = bilerp(z2, 256, qm2, qn2[ni]);
        float z250v = bilerp(z4, 128, qm4, qn4[ni]);
        float s = fast_log1p(acc[mi][ni][r]) + fast_log1p(z80v) + fast_log1p(z250v);
        O[idx] = fast_log1p(bf2f(xb[idx])) - s * (1.0f / 3.0f);
      }
    }
}

// ---------- prep unit (256 threads each) ----------
// u<256: G15 | u<320: G80c | u<336: G250c | u<1872: fused Xb/X2/X4 pooling (x read ONCE)
__device__ __forceinline__ void prep_unit(
    int u, int t, const float* __restrict__ x,
    unsigned short* __restrict__ G15, unsigned short* __restrict__ G80c,
    unsigned short* __restrict__ G250c,
    unsigned short* __restrict__ Xb, unsigned short* __restrict__ X2,
    unsigned short* __restrict__ X4,
    float i2s15, float n15, float i2s80, float n80, float i2s250, float n250) {
  if (u < 256) {
    int gid = u * 256 + t;
    int I = gid >> 7, J0 = (gid & 127) << 2;
    s4v o;
    #pragma unroll
    for (int e = 0; e < 4; ++e) {
      int d = J0 + e - I;
      int ad = d < 0 ? -d : d;
      float v = 0.f;
      if (ad <= 30) v = expf(-(float)(d * d) * i2s15) * n15;
      o[e] = (short)f2bf(v);
    }
    *(s4v*)(G15 + (size_t)gid * 4) = o;
  } else if (u < 320) {
    int lid = (u - 256) * 256 + t;
    int I = lid >> 6, J0 = (lid & 63) << 2;
    s4v o;
    #pragma unroll
    for (int e = 0; e < 4; ++e) {
      float dd = (float)(2 * (I - (J0 + e)));
      float v = 0.f;
      #pragma unroll
      for (int e2 = 0; e2 < 2; ++e2) {
        float uu = dd + 0.5f - (float)e2;
        if (fabsf(uu) <= 160.f) v += expf(-uu * uu * i2s80) * n80;
      }
      o[e] = (short)f2bf(v);
    }
    *(s4v*)(G80c + (size_t)lid * 4) = o;
  } else if (u < 336) {
    int lid = (u - 320) * 256 + t;
    int I = lid >> 5, J0 = (lid & 31) << 2;
    s4v o;
    #pragma unroll
    for (int e = 0; e < 4; ++e) {
      float dd = (float)(4 * (I - (J0 + e)));
      float v = 0.f;
      #pragma unroll
      for (int e2 = 0; e2 < 4; ++e2) {
        float uu = dd + 1.5f - (float)e2;
        if (fabsf(uu) <= 500.f) v += expf(-uu * uu * i2s250) * n250;
      }
      o[e] = (short)f2bf(v);
    }
    *(s4v*)(G250c + (size_t)lid * 4) = o;
  } else {
    // fused pooling: thread owns one 4x4 fine block
    int lid = (u - 336) * 256 + t;          // [0, 24*128*128)
    int img = lid >> 14;
    int rem = lid & 16383;
    int I = rem >> 7, J = rem & 127;        // coarse-4 coords
    const float* p = x + (size_t)img * MAT + (4 * I) * HW + 4 * J;
    f4v r0 = *(const f4v*)p;
    f4v r1 = *(const f4v*)(p + HW);
    f4v r2 = *(const f4v*)(p + 2 * HW);
    f4v r3 = *(const f4v*)(p + 3 * HW);
    unsigned short* xb = Xb + (size_t)img * MAT + (4 * I) * HW + 4 * J;
    {
      s4v b0, b1, b2, b3;
      #pragma unroll
      for (int e = 0; e < 4; ++e) {
        b0[e] = (short)f2bf(r0[e]); b1[e] = (short)f2bf(r1[e]);
        b2[e] = (short)f2bf(r2[e]); b3[e] = (short)f2bf(r3[e]);
      }
      *(s4v*)xb = b0;
      *(s4v*)(xb + HW) = b1;
      *(s4v*)(xb + 2 * HW) = b2;
      *(s4v*)(xb + 3 * HW) = b3;
    }
    float p00 = 0.25f * (r0[0] + r0[1] + r1[0] + r1[1]);
    float p01 = 0.25f * (r0[2] + r0[3] + r1[2] + r1[3]);
    float p10 = 0.25f * (r2[0] + r2[1] + r3[0] + r3[1]);
    float p11 = 0.25f * (r2[2] + r2[3] + r3[2] + r3[3]);
    unsigned short* x2 = X2 + (size_t)img * 65536 + (2 * I) * 256 + 2 * J;
    s2v a, b;
    a[0] = (short)f2bf(p00); a[1] = (short)f2bf(p01);
    b[0] = (short)f2bf(p10); b[1] = (short)f2bf(p11);
    *(s2v*)x2 = a;
    *(s2v*)(x2 + 256) = b;
    X4[(size_t)img * 16384 + I * 128 + J] = f2bf(0.25f * (p00 + p01 + p10 + p11));
  }
}

// ---------- the persistent kernel ----------
__global__ __launch_bounds__(256, 2) void persist_kernel(
    const float* __restrict__ x,
    unsigned short* __restrict__ G15, unsigned short* __restrict__ G80,
    unsigned short* __restrict__ G250,
    unsigned short* __restrict__ Xb, unsigned short* __restrict__ X2,
    unsigned short* __restrict__ X4,
    unsigned short* __restrict__ U15, unsigned short* __restrict__ U80,
    unsigned short* __restrict__ U250,
    float* __restrict__ Z80, float* __restrict__ Z250,
    float* __restrict__ out, int* bar,
    float i2s15, float n15, float i2s80, float n80, float i2s250, float n250) {
  __shared__ __align__(16) short As[2][128 * 64];
  __shared__ __align__(16) short Bs[2][64 * 64];
  int b = blockIdx.x, t = threadIdx.x;

  // P0: prep (1872 units)
  for (int u = b; u < 1872; u += NBLK)
    prep_unit(u, t, x, G15, G80, G250, Xb, X2, X4,
              i2s15, n15, i2s80, n80, i2s250, n250);
  gbar(bar, NBLK);

  // P1: fine pass1 (768) + coarse pass1 (192 + 48)
  for (int j = b; j < 1008; j += NBLK) {
    if (j < 768)       gemm_body<512, unsigned short>(G15, Xb, U15, 30, j, As, Bs, t);
    else if (j < 960)  gemm_body<256, unsigned short>(G80, X2, U80, 80, j - 768, As, Bs, t);
    else               gemm_body<128, unsigned short>(G250, X4, U250, 126, j - 960, As, Bs, t);
  }
  gbar(bar, 2 * NBLK);

  // P2: coarse pass2 (192 + 48)
  for (int j = b; j < 240; j += NBLK) {
    if (j < 192) gemm_body<256, float>(G80, U80, Z80, 80, j, As, Bs, t);
    else         gemm_body<128, float>(G250, U250, Z250, 126, j - 192, As, Bs, t);
  }
  gbar(bar, 3 * NBLK);

  // P3: fine pass2 + combine epilogue (768)
  for (int j = b; j < 768; j += NBLK)
    finep2_body(G15, U15, Xb, Z80, Z250, out, j, As, Bs, t);
}

// ---------- fallback (small ws): full-res per-scale, multi-dispatch ----------
__global__ __launch_bounds__(256) void prep_fb_kernel(
    const float* __restrict__ x,
    unsigned short* __restrict__ G,
    unsigned short* __restrict__ Xb,
    float* __restrict__ out,
    float i2s0, float i2s1, float i2s2,
    float n0, float n1, float n2) {
  int b = blockIdx.x, t = threadIdx.x;
  if (b < 768) {
    int gid = b * 256 + t;
    int s = gid >> 16;
    int rem = gid & 65535;
    int I = rem >> 7, J0 = (rem & 127) << 2;
    float i2s = (s == 0) ? i2s0 : (s == 1 ? i2s1 : i2s2);
    float nrm = (s == 0) ? n0 : (s == 1 ? n1 : n2);
    int band = s == 0 ? 30 : (s == 1 ? 160 : 500);
    s4v o;
    #pragma unroll
    for (int e = 0; e < 4; ++e) {
      int d = J0 + e - I;
      int ad = d < 0 ? -d : d;
      float v = 0.f;
      if (ad <= band) v = expf(-(float)(d * d) * i2s) * nrm;
      o[e] = (short)f2bf(v);
    }
    *(s4v*)(G + (size_t)gid * 4) = o;
  } else {
    int lid = (b - 768) * 256 + t;
    f4v v = *(const f4v*)(x + (size_t)lid * 4);
    s4v bv;
    f4v o;
    #pragma unroll
    for (int e = 0; e < 4; ++e) {
      bv[e] = (short)f2bf(v[e]);
      o[e] = fast_log1p(v[e]);
    }
    *(s4v*)(Xb + (size_t)lid * 4) = bv;
    *(f4v*)(out + (size_t)lid * 4) = o;
  }
}

__global__ __launch_bounds__(256) void gemm_fb_kernel(
    const unsigned short* __restrict__ G, const unsigned short* __restrict__ Xb,
    unsigned short* __restrict__ Ut, int band) {
  __shared__ __align__(16) short As[2][128 * 64];
  __shared__ __align__(16) short Bs[2][64 * 64];
  gemm_body<512, unsigned short>(G, Xb, Ut, band, blockIdx.x, As, Bs, threadIdx.x);
}

__global__ __launch_bounds__(256) void pass2_fb_kernel(
    const unsigned short* __restrict__ G,
    const unsigned short* __restrict__ Ut,
    float* __restrict__ out, int band) {
  __shared__ __align__(16) short As[2][128 * 64];
  __shared__ __align__(16) short Bs[2][64 * 64];
  int bid = blockIdx.x;
  int img = bid >> 5, tile = bid & 31;
  int m0 = (tile >> 3) * 128, n0 = (tile & 7) * 64;
  int t = threadIdx.x;
  int lane = t & 63, w = t >> 6;
  int wr = (w >> 1) * 64, wc = (w & 1) * 32;
  int lrow = lane & 15, lq = lane >> 4;

  f4v acc[4][2];
  #pragma unroll
  for (int mi = 0; mi < 4; ++mi)
    #pragma unroll
    for (int ni = 0; ni < 2; ++ni)
      #pragma unroll
      for (int r = 0; r < 4; ++r) acc[mi][ni][r] = 0.f;

  gemm_core<512>(G + m0 * HW, Ut + img * MAT + n0 * HW,
                 m0, band, As, Bs, w, lane, wr, wc, lrow, lq, acc);

  float* O = out + img * MAT;
  #pragma unroll
  for (int mi = 0; mi < 4; ++mi)
    #pragma unroll
    for (int r = 0; r < 4; ++r) {
      int m = m0 + wr + mi * 16 + lq * 4 + r;
      #pragma unroll
      for (int ni = 0; ni < 2; ++ni) {
        int idx = m * HW + n0 + wc + ni * 16 + lrow;
        O[idx] = O[idx] - fast_log1p(acc[mi][ni][r]) * (1.0f / 3.0f);
      }
    }
}

// ---------- host ----------
extern "C" void kernel_launch(void* const* d_in, const int* in_sizes, int n_in,
                              void* d_out, int out_size, void* d_ws, size_t ws_size,
                              hipStream_t stream) {
  (void)in_sizes; (void)n_in; (void)out_size;
  const float* x = (const float*)d_in[0];
  float* out = (float*)d_out;
  unsigned short* W = (unsigned short*)d_ws;

  static const int scales[3] = {15, 80, 250};
  float i2s[3], nrm[3];
  for (int si = 0; si < 3; ++si) {
    double s = (double)scales[si];
    double S = 0.0;
    for (int c = -2 * scales[si]; c <= 2 * scales[si]; ++c)
      S += exp(-(double)c * (double)c / (2.0 * s * s));
    i2s[si] = (float)(1.0 / (2.0 * s * s));
    nrm[si] = (float)(1.0 / S);
  }

  // workspace layout (units: shorts; float arrays take 2x shorts)
  const size_t oG15 = 0;                     // 512*512
  const size_t oG80 = oG15 + 262144;         // 256*256
  const size_t oG250 = oG80 + 65536;         // 128*128
  const size_t oXb = oG250 + 16384;          // 24*512*512
  const size_t oX2 = oXb + 6291456;          // 24*256*256
  const size_t oX4 = oX2 + 1572864;          // 24*128*128
  const size_t oU15 = oX4 + 393216;          // 24*512*512
  const size_t oU80 = oU15 + 6291456;        // 24*256*256
  const size_t oU250 = oU80 + 1572864;       // 24*128*128
  const size_t oZ80 = oU250 + 393216;        // 24*256*256 f32
  const size_t oZ250 = oZ80 + 3145728;       // 24*128*128 f32
  const size_t endMain = oZ250 + 786432;
  const size_t barOff = ((endMain * 2) + 255) & ~(size_t)255;  // bytes

  if (ws_size >= barOff + 256) {
    unsigned short* G15 = W + oG15;
    unsigned short* G80 = W + oG80;
    unsigned short* G250 = W + oG250;
    unsigned short* Xb = W + oXb;
    unsigned short* X2 = W + oX2;
    unsigned short* X4 = W + oX4;
    unsigned short* U15 = W + oU15;
    unsigned short* U80 = W + oU80;
    unsigned short* U250 = W + oU250;
    float* Z80 = (float*)(W + oZ80);
    float* Z250 = (float*)(W + oZ250);
    int* bar = (int*)((char*)d_ws + barOff);

    hipMemsetAsync(bar, 0, 256, stream);
    persist_kernel<<<NBLK, 256, 0, stream>>>(
        x, G15, G80, G250, Xb, X2, X4, U15, U80, U250, Z80, Z250, out, bar,
        i2s[0], nrm[0], i2s[1], nrm[1], i2s[2], nrm[2]);
  } else {
    // fallback: full-res per-scale (G3 + Xb + Ut = 26.7MB)
    unsigned short* G = W;
    unsigned short* Xb = G + 3 * MAT;
    unsigned short* Ut = Xb + (size_t)NIMG * MAT;
    prep_fb_kernel<<<768 + 6144, 256, 0, stream>>>(
        x, G, Xb, out, i2s[0], i2s[1], i2s[2], nrm[0], nrm[1], nrm[2]);
    static const int bands[3] = {30, 160, 500};
    for (int s = 0; s < 3; ++s) {
      gemm_fb_kernel<<<768, 256, 0, stream>>>(G + s * MAT, Xb, Ut, bands[s]);
      pass2_fb_kernel<<<768, 256, 0, stream>>>(G + s * MAT, Ut, out, bands[s]);
    }
  }
}

// Round 9
// 46.895 us; speedup vs baseline: 9.6438x; 9.6438x over previous
//
#include <hip/hip_runtime.h>
#include <hip/hip_bf16.h>
#include <math.h>

// ---------- types ----------
typedef __attribute__((ext_vector_type(8))) short s8v;   // 8 bf16 - MFMA A/B frag
typedef __attribute__((ext_vector_type(4))) short s4v;   // 4 bf16
typedef __attribute__((ext_vector_type(2))) short s2v;   // 2 bf16
typedef __attribute__((ext_vector_type(4))) float f4v;   // 4 f32 - MFMA C/D frag

#define HW   512
#define NIMG 24
#define MAT  (HW*HW)   // 262144

__device__ __forceinline__ unsigned short f2bf(float f) {
  unsigned u = __builtin_bit_cast(unsigned, f);
  u += 0x7fffu + ((u >> 16) & 1u);
  return (unsigned short)(u >> 16);
}
__device__ __forceinline__ float bf2f(unsigned short b) {
  return __builtin_bit_cast(float, (unsigned)b << 16);
}

// fast log1p for z >= 0: v_log_f32 (log2) * ln2, ~1 ulp on 1+z
__device__ __forceinline__ float fast_log1p(float z) {
  float a = 1.0f + z;
  float l;
#if __has_builtin(__builtin_amdgcn_logf)
  l = __builtin_amdgcn_logf(a);
#else
  asm("v_log_f32 %0, %1" : "=v"(l) : "v"(a));
#endif
  return l * 0.69314718055994531f;
}

// ---------- swizzled LDS staging (proven: 0 bank conflicts) ----------
template<int NROWS, int STRB>
__device__ __forceinline__ void stage_tile(const unsigned short* __restrict__ src,
                                           short* lds, int w, int l) {
  #pragma unroll
  for (int c = 0; c < NROWS / 32; ++c) {
    int cid = c * 4 + w;                   // 1KB chunk-groups
    int chunk = cid * 64 + l;              // 16B chunk id within tile
    int row = chunk >> 3, ch = chunk & 7;
    const char* g = (const char*)src + row * STRB + ((ch ^ (row & 7)) << 4);
    __builtin_amdgcn_global_load_lds(
        (const __attribute__((address_space(1))) void*)g,
        (__attribute__((address_space(3))) void*)(lds + (cid << 9)),
        16, 0, 0);
  }
}

__device__ __forceinline__ s8v lds_frag(const short* base, int row, int chunk) {
  return *(const s8v*)((const char*)base + row * 128 + ((chunk ^ (row & 7)) << 4));
}

// ---------- core banded bf16 GEMM (R5-proven 2-phase loop) ----------
template<int IMGW>
__device__ __forceinline__ void gemm_core(
    const unsigned short* __restrict__ Am,   // A + m0*IMGW
    const unsigned short* __restrict__ Bn,   // Bimg + n0*IMGW
    int m0, int band,
    short (*As)[128 * 64], short (*Bs)[64 * 64],
    int w, int lane, int wr, int wc, int lrow, int lq,
    f4v (&acc)[4][2]) {
  constexpr int STRB = IMGW * 2;
  int klo = m0 - band; if (klo < 0) klo = 0; klo >>= 6;
  int hi = m0 + 128 + band; if (hi > IMGW) hi = IMGW;
  int khi = (hi + 63) >> 6;

  stage_tile<128, STRB>(Am + (klo << 6), As[0], w, lane);
  stage_tile<64, STRB>(Bn + (klo << 6), Bs[0], w, lane);
  __syncthreads();
  int cur = 0;

  for (int kb = klo; kb < khi; ++kb) {
    if (kb + 1 < khi) {   // issue next-tile loads BEFORE compute
      stage_tile<128, STRB>(Am + ((kb + 1) << 6), As[cur ^ 1], w, lane);
      stage_tile<64, STRB>(Bn + ((kb + 1) << 6), Bs[cur ^ 1], w, lane);
    }
    #pragma unroll
    for (int kk = 0; kk < 2; ++kk) {
      s8v af[4], bf[2];
      int chunk = (kk << 2) + lq;
      #pragma unroll
      for (int mi = 0; mi < 4; ++mi)
        af[mi] = lds_frag(As[cur], wr + mi * 16 + lrow, chunk);
      #pragma unroll
      for (int ni = 0; ni < 2; ++ni)
        bf[ni] = lds_frag(Bs[cur], wc + ni * 16 + lrow, chunk);
      #pragma unroll
      for (int mi = 0; mi < 4; ++mi)
        #pragma unroll
        for (int ni = 0; ni < 2; ++ni)
          acc[mi][ni] = __builtin_amdgcn_mfma_f32_16x16x32_bf16(af[mi], bf[ni], acc[mi][ni], 0, 0, 0);
    }
    __syncthreads();      // one vmcnt(0)+barrier per tile
    cur ^= 1;
  }
}

// ---------- generic GEMM block: O[img][m][n] = sum_k A[m][k]*B[img][n][k] ----------
template<int IMGW, typename OT>
__device__ __forceinline__ void gemm_body(
    const unsigned short* __restrict__ A,
    const unsigned short* __restrict__ Bm,
    OT* __restrict__ O,
    int band, int bid,
    short (*As)[128 * 64], short (*Bs)[64 * 64], int t) {
  constexpr int NT = IMGW / 64;
  constexpr int TPI = (IMGW / 128) * NT;
  int img = bid / TPI, tl = bid % TPI;
  int m0 = (tl / NT) * 128, n0 = (tl % NT) * 64;

  int lane = t & 63, w = t >> 6;
  int wr = (w >> 1) * 64, wc = (w & 1) * 32;
  int lrow = lane & 15, lq = lane >> 4;

  f4v acc[4][2];
  #pragma unroll
  for (int mi = 0; mi < 4; ++mi)
    #pragma unroll
    for (int ni = 0; ni < 2; ++ni)
      #pragma unroll
      for (int r = 0; r < 4; ++r) acc[mi][ni][r] = 0.f;

  gemm_core<IMGW>(A + m0 * IMGW, Bm + img * IMGW * IMGW + n0 * IMGW,
                  m0, band, As, Bs, w, lane, wr, wc, lrow, lq, acc);

  OT* Ob = O + img * IMGW * IMGW;
  #pragma unroll
  for (int mi = 0; mi < 4; ++mi)
    #pragma unroll
    for (int r = 0; r < 4; ++r) {
      int m = m0 + wr + mi * 16 + lq * 4 + r;
      #pragma unroll
      for (int ni = 0; ni < 2; ++ni) {
        int n = n0 + wc + ni * 16 + lrow;
        float v = acc[mi][ni][r];
        if constexpr (sizeof(OT) == 2) Ob[m * IMGW + n] = f2bf(v);
        else                           Ob[m * IMGW + n] = v;
      }
    }
}

// ---------- pass1 for all three resolutions in one dispatch ----------
// blocks [0,768): s15 @512 (XCD img-grouped); [768,960): s80 @256; [960,1008): s250 @128
__global__ __launch_bounds__(256) void gemm_tri_kernel(
    const unsigned short* __restrict__ G15, const unsigned short* __restrict__ Xb,
    unsigned short* __restrict__ U15,
    const unsigned short* __restrict__ G80, const unsigned short* __restrict__ X2,
    unsigned short* __restrict__ U80,
    const unsigned short* __restrict__ G250, const unsigned short* __restrict__ X4,
    unsigned short* __restrict__ U250) {
  __shared__ __align__(16) short As[2][128 * 64];
  __shared__ __align__(16) short Bs[2][64 * 64];
  int bid = blockIdx.x, t = threadIdx.x;
  if (bid < 768) {
    int sw = (bid & 7) * 96 + (bid >> 3);   // bijective XCD img-grouping (768%8==0)
    gemm_body<512, unsigned short>(G15, Xb, U15, 30, sw, As, Bs, t);
  } else if (bid < 960) {
    gemm_body<256, unsigned short>(G80, X2, U80, 80, bid - 768, As, Bs, t);
  } else {
    gemm_body<128, unsigned short>(G250, X4, U250, 126, bid - 960, As, Bs, t);
  }
}

// ---------- coarse pass2: Z (float) for s80 and s250 ----------
__global__ __launch_bounds__(256) void gemm_coarse2_kernel(
    const unsigned short* __restrict__ G80, const unsigned short* __restrict__ U80,
    float* __restrict__ Z80,
    const unsigned short* __restrict__ G250, const unsigned short* __restrict__ U250,
    float* __restrict__ Z250) {
  __shared__ __align__(16) short As[2][128 * 64];
  __shared__ __align__(16) short Bs[2][64 * 64];
  int bid = blockIdx.x, t = threadIdx.x;
  if (bid < 192) gemm_body<256, float>(G80, U80, Z80, 80, bid, As, Bs, t);
  else           gemm_body<128, float>(G250, U250, Z250, 126, bid - 192, As, Bs, t);
}

// ---------- fallback full-res pass1 ----------
__global__ __launch_bounds__(256) void gemm_fb_kernel(
    const unsigned short* __restrict__ G, const unsigned short* __restrict__ Xb,
    unsigned short* __restrict__ Ut, int band) {
  __shared__ __align__(16) short As[2][128 * 64];
  __shared__ __align__(16) short Bs[2][64 * 64];
  gemm_body<512, unsigned short>(G, Xb, Ut, band, blockIdx.x, As, Bs, threadIdx.x);
}

// ---------- bilinear sample of coarse float field ----------
__device__ __forceinline__ float bilerp(const float* __restrict__ Z, int W,
                                        float qm, float qn) {
  float fm = floorf(qm), fn = floorf(qn);
  float am = qm - fm, an = qn - fn;
  int i0 = (int)fm, j0 = (int)fn;
  int i1 = i0 + 1, j1 = j0 + 1;
  i0 = i0 < 0 ? 0 : (i0 > W - 1 ? W - 1 : i0);
  i1 = i1 < 0 ? 0 : (i1 > W - 1 ? W - 1 : i1);
  j0 = j0 < 0 ? 0 : (j0 > W - 1 ? W - 1 : j0);
  j1 = j1 < 0 ? 0 : (j1 > W - 1 ? W - 1 : j1);
  const float* r0 = Z + i0 * W;
  const float* r1 = Z + i1 * W;
  float z0 = r0[j0] + an * (r0[j1] - r0[j0]);
  float z1 = r1[j0] + an * (r1[j1] - r1[j0]);
  return z0 + am * (z1 - z0);
}

// ---------- fine pass2 (s15) + combine epilogue ----------
// MODE 0: out = log1p(xb) - (l1p(z15) + l1p(bilerp Z80) + l1p(bilerp Z250))/3
// MODE 1 (fallback): out -= l1p(acc)/3
template<int MODE>
__global__ __launch_bounds__(256) void pass2f_kernel(
    const unsigned short* __restrict__ G,
    const unsigned short* __restrict__ Ut,
    const unsigned short* __restrict__ Xb,
    const float* __restrict__ Z2,
    const float* __restrict__ Z4,
    float* __restrict__ out, int band) {
  __shared__ __align__(16) short As[2][128 * 64];
  __shared__ __align__(16) short Bs[2][64 * 64];

  int bid0 = blockIdx.x;
  int bid = (bid0 & 7) * 96 + (bid0 >> 3);   // XCD img-grouping
  int img = bid >> 5, tile = bid & 31;
  int m0 = (tile >> 3) * 128, n0 = (tile & 7) * 64;

  int t = threadIdx.x;
  int lane = t & 63, w = t >> 6;
  int wr = (w >> 1) * 64, wc = (w & 1) * 32;
  int lrow = lane & 15, lq = lane >> 4;

  f4v acc[4][2];
  #pragma unroll
  for (int mi = 0; mi < 4; ++mi)
    #pragma unroll
    for (int ni = 0; ni < 2; ++ni)
      #pragma unroll
      for (int r = 0; r < 4; ++r) acc[mi][ni][r] = 0.f;

  gemm_core<512>(G + m0 * HW, Ut + img * MAT + n0 * HW,
                 m0, band, As, Bs, w, lane, wr, wc, lrow, lq, acc);

  const unsigned short* xb = Xb + img * MAT;
  float* O = out + img * MAT;

  if (MODE == 0) {
    const float* z2 = Z2 + img * 65536;
    const float* z4 = Z4 + img * 16384;
    float qn2[2], qn4[2];
    int nn[2];
    #pragma unroll
    for (int ni = 0; ni < 2; ++ni) {
      nn[ni] = n0 + wc + ni * 16 + lrow;
      qn2[ni] = 0.5f * nn[ni] - 0.25f;     // coarse-2 col coord
      qn4[ni] = 0.25f * nn[ni] - 0.375f;   // coarse-4 col coord
    }
    #pragma unroll
    for (int mi = 0; mi < 4; ++mi)
      #pragma unroll
      for (int r = 0; r < 4; ++r) {
        int m = m0 + wr + mi * 16 + lq * 4 + r;
        float qm2 = 0.5f * m - 0.25f;
        float qm4 = 0.25f * m - 0.375f;
        #pragma unroll
        for (int ni = 0; ni < 2; ++ni) {
          int idx = m * HW + nn[ni];
          float z80v = bilerp(z2, 256, qm2, qn2[ni]);
          float z250v = bilerp(z4, 128, qm4, qn4[ni]);
          float s = fast_log1p(acc[mi][ni][r]) + fast_log1p(z80v) + fast_log1p(z250v);
          O[idx] = fast_log1p(bf2f(xb[idx])) - s * (1.0f / 3.0f);
        }
      }
  } else {
    #pragma unroll
    for (int mi = 0; mi < 4; ++mi)
      #pragma unroll
      for (int r = 0; r < 4; ++r) {
        int m = m0 + wr + mi * 16 + lq * 4 + r;
        #pragma unroll
        for (int ni = 0; ni < 2; ++ni) {
          int idx = m * HW + n0 + wc + ni * 16 + lrow;
          O[idx] = O[idx] - fast_log1p(acc[mi][ni][r]) * (1.0f / 3.0f);
        }
      }
  }
}

// ---------- prep (fused single-read): G15|G80c|G250c|fused Xb/X2/X4 pooling ----------
// blocks: [0,256) G15 | [256,320) G80c | [320,336) G250c | [336,1872) pooling
// (x is read ONCE; each pooling thread owns a 4x4 fine block -> Xb + X2 + X4)
__global__ __launch_bounds__(256) void prep_fused_kernel(
    const float* __restrict__ x,
    unsigned short* __restrict__ G15, unsigned short* __restrict__ G80c,
    unsigned short* __restrict__ G250c,
    unsigned short* __restrict__ Xb, unsigned short* __restrict__ X2,
    unsigned short* __restrict__ X4,
    float i2s15, float n15, float i2s80, float n80, float i2s250, float n250) {
  int b = blockIdx.x, t = threadIdx.x;
  if (b < 256) {                     // G15: 512x512, g15(j-i), band 30
    int gid = b * 256 + t;
    int I = gid >> 7, J0 = (gid & 127) << 2;
    s4v o;
    #pragma unroll
    for (int e = 0; e < 4; ++e) {
      int d = J0 + e - I;
      int ad = d < 0 ? -d : d;
      float v = 0.f;
      if (ad <= 30) v = expf(-(float)(d * d) * i2s15) * n15;
      o[e] = (short)f2bf(v);
    }
    *(s4v*)(G15 + (size_t)gid * 4) = o;
  } else if (b < 320) {              // G80c: 256x256, sum of 2 fine taps
    int lid = (b - 256) * 256 + t;
    int I = lid >> 6, J0 = (lid & 63) << 2;
    s4v o;
    #pragma unroll
    for (int e = 0; e < 4; ++e) {
      float dd = (float)(2 * (I - (J0 + e)));
      float v = 0.f;
      #pragma unroll
      for (int e2 = 0; e2 < 2; ++e2) {
        float uu = dd + 0.5f - (float)e2;
        if (fabsf(uu) <= 160.f) v += expf(-uu * uu * i2s80) * n80;
      }
      o[e] = (short)f2bf(v);
    }
    *(s4v*)(G80c + (size_t)lid * 4) = o;
  } else if (b < 336) {              // G250c: 128x128, sum of 4 fine taps
    int lid = (b - 320) * 256 + t;
    int I = lid >> 5, J0 = (lid & 31) << 2;
    s4v o;
    #pragma unroll
    for (int e = 0; e < 4; ++e) {
      float dd = (float)(4 * (I - (J0 + e)));
      float v = 0.f;
      #pragma unroll
      for (int e2 = 0; e2 < 4; ++e2) {
        float uu = dd + 1.5f - (float)e2;
        if (fabsf(uu) <= 500.f) v += expf(-uu * uu * i2s250) * n250;
      }
      o[e] = (short)f2bf(v);
    }
    *(s4v*)(G250c + (size_t)lid * 4) = o;
  } else {
    // fused pooling: thread owns one 4x4 fine block (x read once)
    int lid = (b - 336) * 256 + t;          // [0, 24*128*128)
    int img = lid >> 14;
    int rem = lid & 16383;
    int I = rem >> 7, J = rem & 127;        // coarse-4 coords
    const float* p = x + (size_t)img * MAT + (4 * I) * HW + 4 * J;
    f4v r0 = *(const f4v*)p;
    f4v r1 = *(const f4v*)(p + HW);
    f4v r2 = *(const f4v*)(p + 2 * HW);
    f4v r3 = *(const f4v*)(p + 3 * HW);
    unsigned short* xb = Xb + (size_t)img * MAT + (4 * I) * HW + 4 * J;
    {
      s4v b0, b1, b2, b3;
      #pragma unroll
      for (int e = 0; e < 4; ++e) {
        b0[e] = (short)f2bf(r0[e]); b1[e] = (short)f2bf(r1[e]);
        b2[e] = (short)f2bf(r2[e]); b3[e] = (short)f2bf(r3[e]);
      }
      *(s4v*)xb = b0;
      *(s4v*)(xb + HW) = b1;
      *(s4v*)(xb + 2 * HW) = b2;
      *(s4v*)(xb + 3 * HW) = b3;
    }
    float p00 = 0.25f * (r0[0] + r0[1] + r1[0] + r1[1]);
    float p01 = 0.25f * (r0[2] + r0[3] + r1[2] + r1[3]);
    float p10 = 0.25f * (r2[0] + r2[1] + r3[0] + r3[1]);
    float p11 = 0.25f * (r2[2] + r2[3] + r3[2] + r3[3]);
    unsigned short* x2 = X2 + (size_t)img * 65536 + (2 * I) * 256 + 2 * J;
    s2v a, b2v;
    a[0] = (short)f2bf(p00); a[1] = (short)f2bf(p01);
    b2v[0] = (short)f2bf(p10); b2v[1] = (short)f2bf(p11);
    *(s2v*)x2 = a;
    *(s2v*)(x2 + 256) = b2v;
    X4[(size_t)img * 16384 + I * 128 + J] = f2bf(0.25f * (p00 + p01 + p10 + p11));
  }
}

// ---------- prep (fallback): 3 full-res G + Xb + out=log1p(x) ----------
__global__ __launch_bounds__(256) void prep_fb_kernel(
    const float* __restrict__ x,
    unsigned short* __restrict__ G,
    unsigned short* __restrict__ Xb,
    float* __restrict__ out,
    float i2s0, float i2s1, float i2s2,
    float n0, float n1, float n2) {
  int b = blockIdx.x, t = threadIdx.x;
  if (b < 768) {
    int gid = b * 256 + t;
    int s = gid >> 16;
    int rem = gid & 65535;
    int I = rem >> 7, J0 = (rem & 127) << 2;
    float i2s = (s == 0) ? i2s0 : (s == 1 ? i2s1 : i2s2);
    float nrm = (s == 0) ? n0 : (s == 1 ? n1 : n2);
    int band = s == 0 ? 30 : (s == 1 ? 160 : 500);
    s4v o;
    #pragma unroll
    for (int e = 0; e < 4; ++e) {
      int d = J0 + e - I;
      int ad = d < 0 ? -d : d;
      float v = 0.f;
      if (ad <= band) v = expf(-(float)(d * d) * i2s) * nrm;
      o[e] = (short)f2bf(v);
    }
    *(s4v*)(G + (size_t)gid * 4) = o;
  } else {
    int lid = (b - 768) * 256 + t;
    f4v v = *(const f4v*)(x + (size_t)lid * 4);
    s4v bv;
    f4v o;
    #pragma unroll
    for (int e = 0; e < 4; ++e) {
      bv[e] = (short)f2bf(v[e]);
      o[e] = fast_log1p(v[e]);
    }
    *(s4v*)(Xb + (size_t)lid * 4) = bv;
    *(f4v*)(out + (size_t)lid * 4) = o;
  }
}

// ---------- host ----------
extern "C" void kernel_launch(void* const* d_in, const int* in_sizes, int n_in,
                              void* d_out, int out_size, void* d_ws, size_t ws_size,
                              hipStream_t stream) {
  (void)in_sizes; (void)n_in; (void)out_size;
  const float* x = (const float*)d_in[0];
  float* out = (float*)d_out;
  unsigned short* W = (unsigned short*)d_ws;

  static const int scales[3] = {15, 80, 250};
  float i2s[3], nrm[3];
  for (int si = 0; si < 3; ++si) {
    double s = (double)scales[si];
    double S = 0.0;
    for (int c = -2 * scales[si]; c <= 2 * scales[si]; ++c)
      S += exp(-(double)c * (double)c / (2.0 * s * s));
    i2s[si] = (float)(1.0 / (2.0 * s * s));
    nrm[si] = (float)(1.0 / S);
  }

  // main-path workspace layout (units: shorts; float arrays take 2x shorts)
  const size_t oG15 = 0;                     // 512*512
  const size_t oG80 = oG15 + 262144;         // 256*256
  const size_t oG250 = oG80 + 65536;         // 128*128
  const size_t oXb = oG250 + 16384;          // 24*512*512
  const size_t oX2 = oXb + 6291456;          // 24*256*256
  const size_t oX4 = oX2 + 1572864;          // 24*128*128
  const size_t oU15 = oX4 + 393216;          // 24*512*512
  const size_t oU80 = oU15 + 6291456;        // 24*256*256
  const size_t oU250 = oU80 + 1572864;       // 24*128*128
  const size_t oZ80 = oU250 + 393216;        // 24*256*256 f32
  const size_t oZ250 = oZ80 + 3145728;       // 24*128*128 f32
  const size_t endMain = oZ250 + 786432;

  if (ws_size >= endMain * 2) {
    unsigned short* G15 = W + oG15;
    unsigned short* G80 = W + oG80;
    unsigned short* G250 = W + oG250;
    unsigned short* Xb = W + oXb;
    unsigned short* X2 = W + oX2;
    unsigned short* X4 = W + oX4;
    unsigned short* U15 = W + oU15;
    unsigned short* U80 = W + oU80;
    unsigned short* U250 = W + oU250;
    float* Z80 = (float*)(W + oZ80);
    float* Z250 = (float*)(W + oZ250);

    prep_fused_kernel<<<1872, 256, 0, stream>>>(
        x, G15, G80, G250, Xb, X2, X4,
        i2s[0], nrm[0], i2s[1], nrm[1], i2s[2], nrm[2]);
    gemm_tri_kernel<<<1008, 256, 0, stream>>>(
        G15, Xb, U15, G80, X2, U80, G250, X4, U250);
    gemm_coarse2_kernel<<<240, 256, 0, stream>>>(
        G80, U80, Z80, G250, U250, Z250);
    pass2f_kernel<0><<<768, 256, 0, stream>>>(
        G15, U15, Xb, Z80, Z250, out, 30);
  } else {
    // fallback: full-res per-scale (G3 + Xb + Ut = 26.7MB)
    unsigned short* G = W;
    unsigned short* Xb = G + 3 * MAT;
    unsigned short* Ut = Xb + (size_t)NIMG * MAT;
    prep_fb_kernel<<<768 + 6144, 256, 0, stream>>>(
        x, G, Xb, out, i2s[0], i2s[1], i2s[2], nrm[0], nrm[1], nrm[2]);
    static const int bands[3] = {30, 160, 500};
    for (int s = 0; s < 3; ++s) {
      gemm_fb_kernel<<<768, 256, 0, stream>>>(G + s * MAT, Xb, Ut, bands[s]);
      pass2f_kernel<1><<<768, 256, 0, stream>>>(
          G + s * MAT, Ut, Xb, (const float*)nullptr, (const float*)nullptr, out, bands[s]);
    }
  }
}

// Round 10
// 46.648 us; speedup vs baseline: 9.6950x; 1.0053x over previous
//
#include <hip/hip_runtime.h>
#include <hip/hip_bf16.h>
#include <math.h>

// ---------- types ----------
typedef __attribute__((ext_vector_type(8))) short s8v;   // 8 bf16 - MFMA A/B frag
typedef __attribute__((ext_vector_type(4))) short s4v;   // 4 bf16
typedef __attribute__((ext_vector_type(2))) short s2v;   // 2 bf16
typedef __attribute__((ext_vector_type(4))) float f4v;   // 4 f32 - MFMA C/D frag

#define HW   512
#define NIMG 24
#define MAT  (HW*HW)   // 262144

__device__ __forceinline__ unsigned short f2bf(float f) {
  unsigned u = __builtin_bit_cast(unsigned, f);
  u += 0x7fffu + ((u >> 16) & 1u);
  return (unsigned short)(u >> 16);
}
__device__ __forceinline__ float bf2f(unsigned short b) {
  return __builtin_bit_cast(float, (unsigned)b << 16);
}

// fast log1p for z >= 0: v_log_f32 (log2) * ln2, ~1 ulp on 1+z
__device__ __forceinline__ float fast_log1p(float z) {
  float a = 1.0f + z;
  float l;
#if __has_builtin(__builtin_amdgcn_logf)
  l = __builtin_amdgcn_logf(a);
#else
  asm("v_log_f32 %0, %1" : "=v"(l) : "v"(a));
#endif
  return l * 0.69314718055994531f;
}

// ---------- tight 8-aligned K-window for a banded m-tile ----------
// Covers [max(0,m0-band), min(W,m0+128+band)) with the MINIMAL number of
// 64-col K-steps at an 8-elem (16B) aligned origin. k0+64*nkb <= W always.
__device__ __forceinline__ void kwin(int m0, int band, int W, int& k0, int& nkb) {
  int lo = m0 - band; if (lo < 0) lo = 0;
  int hi = m0 + 128 + band; if (hi > W) hi = W;
  int hi8 = (hi + 7) & ~7;
  if (hi8 > W) hi8 = W;           // W is a multiple of 64 -> 8-aligned
  nkb = (hi8 - lo + 63) >> 6;
  k0 = hi8 - (nkb << 6);
  if (k0 < 0) k0 = 0;
}

// ---------- swizzled LDS staging (proven: 0 bank conflicts) ----------
template<int NROWS, int STRB>
__device__ __forceinline__ void stage_tile(const unsigned short* __restrict__ src,
                                           short* lds, int w, int l) {
  #pragma unroll
  for (int c = 0; c < NROWS / 32; ++c) {
    int cid = c * 4 + w;                   // 1KB chunk-groups
    int chunk = cid * 64 + l;              // 16B chunk id within tile
    int row = chunk >> 3, ch = chunk & 7;
    const char* g = (const char*)src + row * STRB + ((ch ^ (row & 7)) << 4);
    __builtin_amdgcn_global_load_lds(
        (const __attribute__((address_space(1))) void*)g,
        (__attribute__((address_space(3))) void*)(lds + (cid << 9)),
        16, 0, 0);
  }
}

__device__ __forceinline__ s8v lds_frag(const short* base, int row, int chunk) {
  return *(const s8v*)((const char*)base + row * 128 + ((chunk ^ (row & 7)) << 4));
}

// ---------- core banded bf16 GEMM (R5-proven 2-phase loop; tight K-window) ----------
template<int IMGW>
__device__ __forceinline__ void gemm_core(
    const unsigned short* __restrict__ Am,   // A + m0*IMGW
    const unsigned short* __restrict__ Bn,   // Bimg + n0*IMGW
    int k0, int nkb,
    short (*As)[128 * 64], short (*Bs)[64 * 64],
    int w, int lane, int wr, int wc, int lrow, int lq,
    f4v (&acc)[4][2]) {
  constexpr int STRB = IMGW * 2;

  stage_tile<128, STRB>(Am + k0, As[0], w, lane);
  stage_tile<64, STRB>(Bn + k0, Bs[0], w, lane);
  __syncthreads();
  int cur = 0;

  for (int kb = 0; kb < nkb; ++kb) {
    if (kb + 1 < nkb) {   // issue next-tile loads BEFORE compute
      int kn = k0 + ((kb + 1) << 6);
      stage_tile<128, STRB>(Am + kn, As[cur ^ 1], w, lane);
      stage_tile<64, STRB>(Bn + kn, Bs[cur ^ 1], w, lane);
    }
    #pragma unroll
    for (int kk = 0; kk < 2; ++kk) {
      s8v af[4], bf[2];
      int chunk = (kk << 2) + lq;
      #pragma unroll
      for (int mi = 0; mi < 4; ++mi)
        af[mi] = lds_frag(As[cur], wr + mi * 16 + lrow, chunk);
      #pragma unroll
      for (int ni = 0; ni < 2; ++ni)
        bf[ni] = lds_frag(Bs[cur], wc + ni * 16 + lrow, chunk);
      #pragma unroll
      for (int mi = 0; mi < 4; ++mi)
        #pragma unroll
        for (int ni = 0; ni < 2; ++ni)
          acc[mi][ni] = __builtin_amdgcn_mfma_f32_16x16x32_bf16(af[mi], bf[ni], acc[mi][ni], 0, 0, 0);
    }
    __syncthreads();      // one vmcnt(0)+barrier per tile
    cur ^= 1;
  }
}

// ---------- generic GEMM block: O[img][m][n] = sum_k A[m][k]*B[img][n][k] ----------
template<int IMGW, typename OT>
__device__ __forceinline__ void gemm_body(
    const unsigned short* __restrict__ A,
    const unsigned short* __restrict__ Bm,
    OT* __restrict__ O,
    int band, int bid,
    short (*As)[128 * 64], short (*Bs)[64 * 64], int t) {
  constexpr int NT = IMGW / 64;
  constexpr int TPI = (IMGW / 128) * NT;
  int img = bid / TPI, tl = bid % TPI;
  int m0 = (tl / NT) * 128, n0 = (tl % NT) * 64;

  int lane = t & 63, w = t >> 6;
  int wr = (w >> 1) * 64, wc = (w & 1) * 32;
  int lrow = lane & 15, lq = lane >> 4;

  f4v acc[4][2];
  #pragma unroll
  for (int mi = 0; mi < 4; ++mi)
    #pragma unroll
    for (int ni = 0; ni < 2; ++ni)
      #pragma unroll
      for (int r = 0; r < 4; ++r) acc[mi][ni][r] = 0.f;

  int k0, nkb;
  kwin(m0, band, IMGW, k0, nkb);
  gemm_core<IMGW>(A + m0 * IMGW, Bm + img * IMGW * IMGW + n0 * IMGW,
                  k0, nkb, As, Bs, w, lane, wr, wc, lrow, lq, acc);

  OT* Ob = O + img * IMGW * IMGW;
  #pragma unroll
  for (int mi = 0; mi < 4; ++mi)
    #pragma unroll
    for (int r = 0; r < 4; ++r) {
      int m = m0 + wr + mi * 16 + lq * 4 + r;
      #pragma unroll
      for (int ni = 0; ni < 2; ++ni) {
        int n = n0 + wc + ni * 16 + lrow;
        float v = acc[mi][ni][r];
        if constexpr (sizeof(OT) == 2) Ob[m * IMGW + n] = f2bf(v);
        else                           Ob[m * IMGW + n] = v;
      }
    }
}

// ---------- pass1 for all three resolutions in one dispatch ----------
// blocks [0,240): coarse p1 (s80, s250) — longer jobs first for packing;
// [240,1008): s15 @512 (XCD img-grouped).
__global__ __launch_bounds__(256) void gemm_tri_kernel(
    const unsigned short* __restrict__ G15, const unsigned short* __restrict__ Xb,
    unsigned short* __restrict__ U15,
    const unsigned short* __restrict__ G80, const unsigned short* __restrict__ X2,
    unsigned short* __restrict__ U80,
    const unsigned short* __restrict__ G250, const unsigned short* __restrict__ X4,
    unsigned short* __restrict__ U250) {
  __shared__ __align__(16) short As[2][128 * 64];
  __shared__ __align__(16) short Bs[2][64 * 64];
  int bid = blockIdx.x, t = threadIdx.x;
  if (bid < 192) {
    gemm_body<256, unsigned short>(G80, X2, U80, 80, bid, As, Bs, t);
  } else if (bid < 240) {
    gemm_body<128, unsigned short>(G250, X4, U250, 126, bid - 192, As, Bs, t);
  } else {
    int fb = bid - 240;
    int sw = (fb & 7) * 96 + (fb >> 3);   // bijective XCD img-grouping (768%8==0)
    gemm_body<512, unsigned short>(G15, Xb, U15, 30, sw, As, Bs, t);
  }
}

// ---------- coarse pass2: Z (float) for s80 and s250 ----------
__global__ __launch_bounds__(256) void gemm_coarse2_kernel(
    const unsigned short* __restrict__ G80, const unsigned short* __restrict__ U80,
    float* __restrict__ Z80,
    const unsigned short* __restrict__ G250, const unsigned short* __restrict__ U250,
    float* __restrict__ Z250) {
  __shared__ __align__(16) short As[2][128 * 64];
  __shared__ __align__(16) short Bs[2][64 * 64];
  int bid = blockIdx.x, t = threadIdx.x;
  if (bid < 192) gemm_body<256, float>(G80, U80, Z80, 80, bid, As, Bs, t);
  else           gemm_body<128, float>(G250, U250, Z250, 126, bid - 192, As, Bs, t);
}

// ---------- fallback full-res pass1 ----------
__global__ __launch_bounds__(256) void gemm_fb_kernel(
    const unsigned short* __restrict__ G, const unsigned short* __restrict__ Xb,
    unsigned short* __restrict__ Ut, int band) {
  __shared__ __align__(16) short As[2][128 * 64];
  __shared__ __align__(16) short Bs[2][64 * 64];
  gemm_body<512, unsigned short>(G, Xb, Ut, band, blockIdx.x, As, Bs, threadIdx.x);
}

// ---------- bilinear sample of coarse float field ----------
__device__ __forceinline__ float bilerp(const float* __restrict__ Z, int W,
                                        float qm, float qn) {
  float fm = floorf(qm), fn = floorf(qn);
  float am = qm - fm, an = qn - fn;
  int i0 = (int)fm, j0 = (int)fn;
  int i1 = i0 + 1, j1 = j0 + 1;
  i0 = i0 < 0 ? 0 : (i0 > W - 1 ? W - 1 : i0);
  i1 = i1 < 0 ? 0 : (i1 > W - 1 ? W - 1 : i1);
  j0 = j0 < 0 ? 0 : (j0 > W - 1 ? W - 1 : j0);
  j1 = j1 < 0 ? 0 : (j1 > W - 1 ? W - 1 : j1);
  const float* r0 = Z + i0 * W;
  const float* r1 = Z + i1 * W;
  float z0 = r0[j0] + an * (r0[j1] - r0[j0]);
  float z1 = r1[j0] + an * (r1[j1] - r1[j0]);
  return z0 + am * (z1 - z0);
}

// ---------- fine pass2 (s15) + combine epilogue ----------
// MODE 0: out = log1p(xb) - (l1p(z15) + l1p(bilerp Z80) + l1p(bilerp Z250))/3
// MODE 1 (fallback): out -= l1p(acc)/3
template<int MODE>
__global__ __launch_bounds__(256) void pass2f_kernel(
    const unsigned short* __restrict__ G,
    const unsigned short* __restrict__ Ut,
    const unsigned short* __restrict__ Xb,
    const float* __restrict__ Z2,
    const float* __restrict__ Z4,
    float* __restrict__ out, int band) {
  __shared__ __align__(16) short As[2][128 * 64];
  __shared__ __align__(16) short Bs[2][64 * 64];

  int bid0 = blockIdx.x;
  int bid = (bid0 & 7) * 96 + (bid0 >> 3);   // XCD img-grouping
  int img = bid >> 5, tile = bid & 31;
  int m0 = (tile >> 3) * 128, n0 = (tile & 7) * 64;

  int t = threadIdx.x;
  int lane = t & 63, w = t >> 6;
  int wr = (w >> 1) * 64, wc = (w & 1) * 32;
  int lrow = lane & 15, lq = lane >> 4;

  f4v acc[4][2];
  #pragma unroll
  for (int mi = 0; mi < 4; ++mi)
    #pragma unroll
    for (int ni = 0; ni < 2; ++ni)
      #pragma unroll
      for (int r = 0; r < 4; ++r) acc[mi][ni][r] = 0.f;

  int k0, nkb;
  kwin(m0, band, HW, k0, nkb);
  gemm_core<512>(G + m0 * HW, Ut + img * MAT + n0 * HW,
                 k0, nkb, As, Bs, w, lane, wr, wc, lrow, lq, acc);

  const unsigned short* xb = Xb + img * MAT;
  float* O = out + img * MAT;

  if (MODE == 0) {
    const float* z2 = Z2 + img * 65536;
    const float* z4 = Z4 + img * 16384;
    float qn2[2], qn4[2];
    int nn[2];
    #pragma unroll
    for (int ni = 0; ni < 2; ++ni) {
      nn[ni] = n0 + wc + ni * 16 + lrow;
      qn2[ni] = 0.5f * nn[ni] - 0.25f;     // coarse-2 col coord
      qn4[ni] = 0.25f * nn[ni] - 0.375f;   // coarse-4 col coord
    }
    #pragma unroll
    for (int mi = 0; mi < 4; ++mi)
      #pragma unroll
      for (int r = 0; r < 4; ++r) {
        int m = m0 + wr + mi * 16 + lq * 4 + r;
        float qm2 = 0.5f * m - 0.25f;
        float qm4 = 0.25f * m - 0.375f;
        #pragma unroll
        for (int ni = 0; ni < 2; ++ni) {
          int idx = m * HW + nn[ni];
          float z80v = bilerp(z2, 256, qm2, qn2[ni]);
          float z250v = bilerp(z4, 128, qm4, qn4[ni]);
          float s = fast_log1p(acc[mi][ni][r]) + fast_log1p(z80v) + fast_log1p(z250v);
          O[idx] = fast_log1p(bf2f(xb[idx])) - s * (1.0f / 3.0f);
        }
      }
  } else {
    #pragma unroll
    for (int mi = 0; mi < 4; ++mi)
      #pragma unroll
      for (int r = 0; r < 4; ++r) {
        int m = m0 + wr + mi * 16 + lq * 4 + r;
        #pragma unroll
        for (int ni = 0; ni < 2; ++ni) {
          int idx = m * HW + n0 + wc + ni * 16 + lrow;
          O[idx] = O[idx] - fast_log1p(acc[mi][ni][r]) * (1.0f / 3.0f);
        }
      }
  }
}

// ---------- prep (fused single-read): G15|G80c|G250c|fused Xb/X2/X4 pooling ----------
// blocks: [0,256) G15 | [256,320) G80c | [320,336) G250c | [336,1872) pooling
// (x is read ONCE; each pooling thread owns a 4x4 fine block -> Xb + X2 + X4)
__global__ __launch_bounds__(256) void prep_fused_kernel(
    const float* __restrict__ x,
    unsigned short* __restrict__ G15, unsigned short* __restrict__ G80c,
    unsigned short* __restrict__ G250c,
    unsigned short* __restrict__ Xb, unsigned short* __restrict__ X2,
    unsigned short* __restrict__ X4,
    float i2s15, float n15, float i2s80, float n80, float i2s250, float n250) {
  int b = blockIdx.x, t = threadIdx.x;
  if (b < 256) {                     // G15: 512x512, g15(j-i), band 30
    int gid = b * 256 + t;
    int I = gid >> 7, J0 = (gid & 127) << 2;
    s4v o;
    #pragma unroll
    for (int e = 0; e < 4; ++e) {
      int d = J0 + e - I;
      int ad = d < 0 ? -d : d;
      float v = 0.f;
      if (ad <= 30) v = expf(-(float)(d * d) * i2s15) * n15;
      o[e] = (short)f2bf(v);
    }
    *(s4v*)(G15 + (size_t)gid * 4) = o;
  } else if (b < 320) {              // G80c: 256x256, sum of 2 fine taps
    int lid = (b - 256) * 256 + t;
    int I = lid >> 6, J0 = (lid & 63) << 2;
    s4v o;
    #pragma unroll
    for (int e = 0; e < 4; ++e) {
      float dd = (float)(2 * (I - (J0 + e)));
      float v = 0.f;
      #pragma unroll
      for (int e2 = 0; e2 < 2; ++e2) {
        float uu = dd + 0.5f - (float)e2;
        if (fabsf(uu) <= 160.f) v += expf(-uu * uu * i2s80) * n80;
      }
      o[e] = (short)f2bf(v);
    }
    *(s4v*)(G80c + (size_t)lid * 4) = o;
  } else if (b < 336) {              // G250c: 128x128, sum of 4 fine taps
    int lid = (b - 320) * 256 + t;
    int I = lid >> 5, J0 = (lid & 31) << 2;
    s4v o;
    #pragma unroll
    for (int e = 0; e < 4; ++e) {
      float dd = (float)(4 * (I - (J0 + e)));
      float v = 0.f;
      #pragma unroll
      for (int e2 = 0; e2 < 4; ++e2) {
        float uu = dd + 1.5f - (float)e2;
        if (fabsf(uu) <= 500.f) v += expf(-uu * uu * i2s250) * n250;
      }
      o[e] = (short)f2bf(v);
    }
    *(s4v*)(G250c + (size_t)lid * 4) = o;
  } else {
    // fused pooling: thread owns one 4x4 fine block (x read once)
    int lid = (b - 336) * 256 + t;          // [0, 24*128*128)
    int img = lid >> 14;
    int rem = lid & 16383;
    int I = rem >> 7, J = rem & 127;        // coarse-4 coords
    const float* p = x + (size_t)img * MAT + (4 * I) * HW + 4 * J;
    f4v r0 = *(const f4v*)p;
    f4v r1 = *(const f4v*)(p + HW);
    f4v r2 = *(const f4v*)(p + 2 * HW);
    f4v r3 = *(const f4v*)(p + 3 * HW);
    unsigned short* xb = Xb + (size_t)img * MAT + (4 * I) * HW + 4 * J;
    {
      s4v b0, b1, b2, b3;
      #pragma unroll
      for (int e = 0; e < 4; ++e) {
        b0[e] = (short)f2bf(r0[e]); b1[e] = (short)f2bf(r1[e]);
        b2[e] = (short)f2bf(r2[e]); b3[e] = (short)f2bf(r3[e]);
      }
      *(s4v*)xb = b0;
      *(s4v*)(xb + HW) = b1;
      *(s4v*)(xb + 2 * HW) = b2;
      *(s4v*)(xb + 3 * HW) = b3;
    }
    float p00 = 0.25f * (r0[0] + r0[1] + r1[0] + r1[1]);
    float p01 = 0.25f * (r0[2] + r0[3] + r1[2] + r1[3]);
    float p10 = 0.25f * (r2[0] + r2[1] + r3[0] + r3[1]);
    float p11 = 0.25f * (r2[2] + r2[3] + r3[2] + r3[3]);
    unsigned short* x2 = X2 + (size_t)img * 65536 + (2 * I) * 256 + 2 * J;
    s2v a, b2v;
    a[0] = (short)f2bf(p00); a[1] = (short)f2bf(p01);
    b2v[0] = (short)f2bf(p10); b2v[1] = (short)f2bf(p11);
    *(s2v*)x2 = a;
    *(s2v*)(x2 + 256) = b2v;
    X4[(size_t)img * 16384 + I * 128 + J] = f2bf(0.25f * (p00 + p01 + p10 + p11));
  }
}

// ---------- prep (fallback): 3 full-res G + Xb + out=log1p(x) ----------
__global__ __launch_bounds__(256) void prep_fb_kernel(
    const float* __restrict__ x,
    unsigned short* __restrict__ G,
    unsigned short* __restrict__ Xb,
    float* __restrict__ out,
    float i2s0, float i2s1, float i2s2,
    float n0, float n1, float n2) {
  int b = blockIdx.x, t = threadIdx.x;
  if (b < 768) {
    int gid = b * 256 + t;
    int s = gid >> 16;
    int rem = gid & 65535;
    int I = rem >> 7, J0 = (rem & 127) << 2;
    float i2s = (s == 0) ? i2s0 : (s == 1 ? i2s1 : i2s2);
    float nrm = (s == 0) ? n0 : (s == 1 ? n1 : n2);
    int band = s == 0 ? 30 : (s == 1 ? 160 : 500);
    s4v o;
    #pragma unroll
    for (int e = 0; e < 4; ++e) {
      int d = J0 + e - I;
      int ad = d < 0 ? -d : d;
      float v = 0.f;
      if (ad <= band) v = expf(-(float)(d * d) * i2s) * nrm;
      o[e] = (short)f2bf(v);
    }
    *(s4v*)(G + (size_t)gid * 4) = o;
  } else {
    int lid = (b - 768) * 256 + t;
    f4v v = *(const f4v*)(x + (size_t)lid * 4);
    s4v bv;
    f4v o;
    #pragma unroll
    for (int e = 0; e < 4; ++e) {
      bv[e] = (short)f2bf(v[e]);
      o[e] = fast_log1p(v[e]);
    }
    *(s4v*)(Xb + (size_t)lid * 4) = bv;
    *(f4v*)(out + (size_t)lid * 4) = o;
  }
}

// ---------- host ----------
extern "C" void kernel_launch(void* const* d_in, const int* in_sizes, int n_in,
                              void* d_out, int out_size, void* d_ws, size_t ws_size,
                              hipStream_t stream) {
  (void)in_sizes; (void)n_in; (void)out_size;
  const float* x = (const float*)d_in[0];
  float* out = (float*)d_out;
  unsigned short* W = (unsigned short*)d_ws;

  static const int scales[3] = {15, 80, 250};
  float i2s[3], nrm[3];
  for (int si = 0; si < 3; ++si) {
    double s = (double)scales[si];
    double S = 0.0;
    for (int c = -2 * scales[si]; c <= 2 * scales[si]; ++c)
      S += exp(-(double)c * (double)c / (2.0 * s * s));
    i2s[si] = (float)(1.0 / (2.0 * s * s));
    nrm[si] = (float)(1.0 / S);
  }

  // main-path workspace layout (units: shorts; float arrays take 2x shorts)
  const size_t oG15 = 0;                     // 512*512
  const size_t oG80 = oG15 + 262144;         // 256*256
  const size_t oG250 = oG80 + 65536;         // 128*128
  const size_t oXb = oG250 + 16384;          // 24*512*512
  const size_t oX2 = oXb + 6291456;          // 24*256*256
  const size_t oX4 = oX2 + 1572864;          // 24*128*128
  const size_t oU15 = oX4 + 393216;          // 24*512*512
  const size_t oU80 = oU15 + 6291456;        // 24*256*256
  const size_t oU250 = oU80 + 1572864;       // 24*128*128
  const size_t oZ80 = oU250 + 393216;        // 24*256*256 f32
  const size_t oZ250 = oZ80 + 3145728;       // 24*128*128 f32
  const size_t endMain = oZ250 + 786432;

  if (ws_size >= endMain * 2) {
    unsigned short* G15 = W + oG15;
    unsigned short* G80 = W + oG80;
    unsigned short* G250 = W + oG250;
    unsigned short* Xb = W + oXb;
    unsigned short* X2 = W + oX2;
    unsigned short* X4 = W + oX4;
    unsigned short* U15 = W + oU15;
    unsigned short* U80 = W + oU80;
    unsigned short* U250 = W + oU250;
    float* Z80 = (float*)(W + oZ80);
    float* Z250 = (float*)(W + oZ250);

    prep_fused_kernel<<<1872, 256, 0, stream>>>(
        x, G15, G80, G250, Xb, X2, X4,
        i2s[0], nrm[0], i2s[1], nrm[1], i2s[2], nrm[2]);
    gemm_tri_kernel<<<1008, 256, 0, stream>>>(
        G15, Xb, U15, G80, X2, U80, G250, X4, U250);
    gemm_coarse2_kernel<<<240, 256, 0, stream>>>(
        G80, U80, Z80, G250, U250, Z250);
    pass2f_kernel<0><<<768, 256, 0, stream>>>(
        G15, U15, Xb, Z80, Z250, out, 30);
  } else {
    // fallback: full-res per-scale (G3 + Xb + Ut = 26.7MB)
    unsigned short* G = W;
    unsigned short* Xb = G + 3 * MAT;
    unsigned short* Ut = Xb + (size_t)NIMG * MAT;
    prep_fb_kernel<<<768 + 6144, 256, 0, stream>>>(
        x, G, Xb, out, i2s[0], i2s[1], i2s[2], nrm[0], nrm[1], nrm[2]);
    static const int bands[3] = {30, 160, 500};
    for (int s = 0; s < 3; ++s) {
      gemm_fb_kernel<<<768, 256, 0, stream>>>(G + s * MAT, Xb, Ut, bands[s]);
      pass2f_kernel<1><<<768, 256, 0, stream>>>(
          G + s * MAT, Ut, Xb, (const float*)nullptr, (const float*)nullptr, out, bands[s]);
    }
  }
}